// Round 1
// baseline (73.760 us; speedup 1.0000x reference)
//
#include <hip/hip_runtime.h>

// STFT_7653631721942: STFT -> mag/phase recombine -> ISTFT with pinv basis +
// window-sum normalization. Mathematically this pipeline is the IDENTITY on
// the output window:
//   - recomb == ft  (mag*cos(atan2(i,r)) = r, mag*sin = i)
//   - pinv(F)F = I (F full column rank) => contrib[t,k] = w^2[k]*frame[k]/scale
//   - overlap-add / wss * scale => inv[p] = xpad[p] wherever wss[p] > tiny
//   - the output slice p in [512, 524800) lies entirely in the un-padded
//     region with wss >= 0.25, so output == input exactly.
// Hence: vectorized d2d copy, 8x524288 f32 = 16 MiB each way.

__global__ __launch_bounds__(256) void stft_identity_copy(
    const float4* __restrict__ in, float4* __restrict__ out, int n4) {
    int i = blockIdx.x * blockDim.x + threadIdx.x;
    if (i < n4) out[i] = in[i];
}

__global__ __launch_bounds__(256) void stft_identity_copy_tail(
    const float* __restrict__ in, float* __restrict__ out, int start, int n) {
    int i = start + blockIdx.x * blockDim.x + threadIdx.x;
    if (i < n) out[i] = in[i];
}

extern "C" void kernel_launch(void* const* d_in, const int* in_sizes, int n_in,
                              void* d_out, int out_size, void* d_ws, size_t ws_size,
                              hipStream_t stream) {
    const float* in = (const float*)d_in[0];   // input_data, 8 x 524288 f32
    float* out = (float*)d_out;                // 8 x 1 x 524288 f32

    int n = out_size;          // 4194304
    int n4 = n >> 2;           // 1048576 float4s (n is divisible by 4)

    const int block = 256;
    int grid = (n4 + block - 1) / block;
    stft_identity_copy<<<grid, block, 0, stream>>>(
        (const float4*)in, (float4*)out, n4);

    int tail_start = n4 << 2;
    int tail = n - tail_start;  // 0 for this problem, kept for safety
    if (tail > 0) {
        stft_identity_copy_tail<<<1, block, 0, stream>>>(in, out, tail_start, n);
    }
}